// Round 11
// baseline (812.212 us; speedup 1.0000x reference)
//
#include <hip/hip_runtime.h>
#include <hip/hip_bf16.h>
#include <stdint.h>

#define HW 8192
typedef short short8 __attribute__((ext_vector_type(8)));
typedef float f32x4 __attribute__((ext_vector_type(4)));

__device__ __forceinline__ float b2f(unsigned short u) {
    union { unsigned int i; float f; } x; x.i = ((unsigned int)u) << 16; return x.f;
}
__device__ __forceinline__ unsigned short f2b(float f) {
    union { float f; unsigned int i; } x; x.f = f;
    unsigned int lsb = (x.i >> 16) & 1u;
    x.i += 0x7fffu + lsb;
    return (unsigned short)(x.i >> 16);
}

// ---------------------------------------------------------------------------
// Wb[tap][co][ci] bf16, co 0..383 (qk then v).  Also Wt[d][k] = bf16(Wout^T).
// ---------------------------------------------------------------------------
__global__ void cast_w_kernel(const float* __restrict__ Wqk,
                              const float* __restrict__ Wv,
                              const float* __restrict__ Wout,
                              unsigned short* __restrict__ Wb,
                              unsigned short* __restrict__ Wt)
{
    const int co = blockIdx.x;            // 0..383
    const int t  = threadIdx.x;
    const float* src = (co < 256) ? (Wqk + (size_t)co * 576)
                                  : (Wv + (size_t)(co - 256) * 576);
    for (int idx = t; idx < 576; idx += 256) {
        const int ci  = idx / 9;
        const int tap = idx - ci * 9;
        Wb[(size_t)tap * (384 * 64) + co * 64 + ci] = f2b(src[idx]);
    }
    if (co < 64 && t < 128) Wt[co * 128 + t] = f2b(Wout[t * 64 + co]);
}

// ---------------------------------------------------------------------------
// x f32 NCHW -> xb bf16 NHWC ([n][pix][ci]), transposed through LDS.
// ---------------------------------------------------------------------------
__launch_bounds__(256)
__global__ void cast_x_kernel(const float* __restrict__ x,
                              unsigned short* __restrict__ xb)
{
    __shared__ __align__(16) unsigned short xt[256 * 64];   // [p][ci] swizzled
    const int t  = threadIdx.x;
    const int pc = blockIdx.x;   // 0..31
    const int n  = blockIdx.y;
    const size_t p0 = (size_t)pc * 256;

    const int ci0 = (t >> 6) * 16;
    const int pl  = (t & 63) * 4;
    unsigned short tmp[16][4];
    #pragma unroll
    for (int i = 0; i < 16; ++i) {
        const float4 v = *reinterpret_cast<const float4*>(
            x + ((size_t)n * 64 + ci0 + i) * HW + p0 + pl);
        tmp[i][0] = f2b(v.x); tmp[i][1] = f2b(v.y);
        tmp[i][2] = f2b(v.z); tmp[i][3] = f2b(v.w);
    }
    #pragma unroll
    for (int p = 0; p < 4; ++p) {
        const int pp = pl + p;
        #pragma unroll
        for (int half = 0; half < 2; ++half) {
            short8 v;
            #pragma unroll
            for (int j = 0; j < 8; ++j) v[j] = (short)tmp[half * 8 + j][p];
            const int gx = (ci0 >> 3) + half;
            *reinterpret_cast<short8*>(&xt[pp * 64 + ((gx ^ (pp & 7)) << 3)]) = v;
        }
    }
    __syncthreads();
    #pragma unroll
    for (int i = 0; i < 8; ++i) {
        const int id = t + i * 256;
        const int pp = id >> 3, gx = id & 7;
        const uint4 v = *reinterpret_cast<const uint4*>(
            &xt[pp * 64 + ((gx ^ (pp & 7)) << 3)]);
        *reinterpret_cast<uint4*>(
            &xb[((size_t)n * HW + p0 + pp) * 64 + gx * 8]) = v;
    }
}

// ---------------------------------------------------------------------------
// Implicit-GEMM conv (the 280 us / 37% MfmaUtil variant).  Epilogue LDS
// scatter now granule-XOR-swizzled: write banks 8-way -> ~free.
// ---------------------------------------------------------------------------
__launch_bounds__(512, 4)
__global__ void conv_mfma_kernel(const unsigned short* __restrict__ xb,
                                 const unsigned short* __restrict__ Wb,
                                 const float* __restrict__ bqk,
                                 const float* __restrict__ bv,
                                 unsigned short* __restrict__ qk_buf,
                                 unsigned short* __restrict__ v_buf)
{
    __shared__ __align__(16) unsigned short x_s[340 * 64];   // 43520 B
    __shared__ __align__(16) unsigned short w_s[128 * 64];   // 16384 B (reused as epilogue buf)
    __shared__ float bias_s[384];

    const int t   = threadIdx.x;
    const int bid = blockIdx.x;
    const int wg  = (bid & 7) * 256 + (bid >> 3);   // XCD swizzle (2048 % 8 == 0)
    const int tile = wg & 31;
    const int n    = wg >> 5;
    const int i0 = (tile >> 2) * 8;
    const int j0 = (tile & 3) * 32;

    if (t < 384) bias_s[t] = (t < 256) ? bqk[t] : bv[t - 256];

    // ---- stage x halo: 340 positions x 8 granules ----
    for (int id = t; id < 340 * 8; id += 512) {
        const int pos = id >> 3, g = id & 7;
        const int r = pos / 34, c = pos - r * 34;
        const int gi = i0 - 1 + r, gj = j0 - 1 + c;
        uint4 v = {0u, 0u, 0u, 0u};
        if ((unsigned)gi < 64u && (unsigned)gj < 128u)
            v = *reinterpret_cast<const uint4*>(
                &xb[((size_t)n * HW + gi * 128 + gj) * 64 + g * 8]);
        *reinterpret_cast<uint4*>(&x_s[pos * 64 + ((g ^ (pos & 7)) << 3)]) = v;
    }

    // ---- W staging roles ----
    const int wco = t >> 3;        // 0..63 (plus +64 for 2nd task)
    const int wgw = t & 7;
    const int wdst0 = wco * 64 + ((wgw ^ (wco & 7)) << 3);
    const int wdst1 = (wco + 64) * 64 + ((wgw ^ ((wco + 64) & 7)) << 3);

    // stage W for step 0 (cb0, tap0)
    *reinterpret_cast<uint4*>(&w_s[wdst0]) =
        *reinterpret_cast<const uint4*>(&Wb[(size_t)wco * 64 + wgw * 8]);
    *reinterpret_cast<uint4*>(&w_s[wdst1]) =
        *reinterpret_cast<const uint4*>(&Wb[(size_t)(wco + 64) * 64 + wgw * 8]);
    __syncthreads();

    // ---- wave decomposition ----
    const int lane15 = t & 15;
    const int lg     = (t >> 4) & 3;
    const int wid    = t >> 6;
    const int wco0   = (wid >> 2) * 64;
    const int pq     = wid & 3;

    f32x4 acc[4][4];
    #pragma unroll
    for (int m = 0; m < 4; ++m)
        #pragma unroll
        for (int r = 0; r < 4; ++r) acc[m][r] = (f32x4){0.f, 0.f, 0.f, 0.f};

    int cb = 0, tap = 0;
    for (int s = 0; s < 27; ++s) {
        // prefetch next step's W
        uint4 wpre0, wpre1;
        if (s < 26) {
            int tap2 = tap + 1, cb2 = cb;
            if (tap2 == 9) { tap2 = 0; cb2 = cb + 1; }
            const unsigned short* wsrc = Wb + ((size_t)tap2 * 384 + cb2 * 128) * 64;
            wpre0 = *reinterpret_cast<const uint4*>(wsrc + wco * 64 + wgw * 8);
            wpre1 = *reinterpret_cast<const uint4*>(wsrc + (wco + 64) * 64 + wgw * 8);
        }
        const int di = (tap * 11) >> 5;      // tap/3
        const int dj = tap - di * 3;

        #pragma unroll
        for (int kc = 0; kc < 2; ++kc) {
            short8 af[4], bf[4];
            #pragma unroll
            for (int m = 0; m < 4; ++m) {
                const int co_l = wco0 + m * 16 + lane15;
                af[m] = *reinterpret_cast<const short8*>(
                    &w_s[co_l * 64 + (((kc * 4 + lg) ^ (co_l & 7)) << 3)]);
            }
            #pragma unroll
            for (int r = 0; r < 4; ++r) {
                const int pos = (pq * 2 + (r >> 1) + di) * 34 + (r & 1) * 16 + lane15 + dj;
                bf[r] = *reinterpret_cast<const short8*>(
                    &x_s[pos * 64 + (((kc * 4 + lg) ^ (pos & 7)) << 3)]);
            }
            #pragma unroll
            for (int m = 0; m < 4; ++m)
                #pragma unroll
                for (int r = 0; r < 4; ++r)
                    acc[m][r] = __builtin_amdgcn_mfma_f32_16x16x32_bf16(
                        af[m], bf[r], acc[m][r], 0, 0, 0);
        }

        if (tap == 8) {
            // ---- epilogue for this cb: swizzled transpose through w_s ----
            const bool is_v = (cb == 2);
            #pragma unroll
            for (int p4 = 0; p4 < 4; ++p4) {
                __syncthreads();
                const int hb = p4 >> 1, mp = (p4 & 1) * 2;
                if ((wid >> 2) == hb) {
                    #pragma unroll
                    for (int mi = 0; mi < 2; ++mi) {
                        #pragma unroll
                        for (int r = 0; r < 4; ++r) {
                            const int pix = (pq * 2 + (r >> 1)) * 32 + (r & 1) * 16 + lane15;
                            #pragma unroll
                            for (int reg = 0; reg < 4; ++reg) {
                                const int cw = mi * 16 + lg * 4 + reg;
                                const int co_tile = hb * 64 + mp * 16 + cw;
                                float v;
                                if (p4 == 0)      v = acc[0 + mi][r][reg];
                                else if (p4 == 1) v = acc[2 + mi][r][reg];
                                else if (p4 == 2) v = acc[0 + mi][r][reg];
                                else              v = acc[2 + mi][r][reg];
                                const int phys = cw * 256 + (pix & 7)
                                    + ((((pix >> 3) ^ cw) & 31) << 3);
                                w_s[phys] = f2b(v + bias_s[cb * 128 + co_tile]);
                            }
                        }
                    }
                }
                __syncthreads();
                #pragma unroll
                for (int i = 0; i < 2; ++i) {
                    const int e = t * 2 + i;
                    const int co_w = e >> 5, ch = e & 31;   // ch = logical 8-px granule
                    const int pg = (ch ^ co_w) & 31;        // physical granule
                    const uint4 v = *reinterpret_cast<const uint4*>(
                        &w_s[co_w * 256 + (pg << 3)]);
                    const int pix0 = ch * 8;
                    const int co_tile = p4 * 32 + co_w;
                    const int row = pix0 >> 5, cc = pix0 & 31;
                    unsigned short* dst = is_v
                        ? (v_buf + ((size_t)n * 128 + co_tile) * HW)
                        : (qk_buf + ((size_t)n * 256 + cb * 128 + co_tile) * HW);
                    *reinterpret_cast<uint4*>(&dst[(i0 + row) * 128 + j0 + cc]) = v;
                }
            }
            #pragma unroll
            for (int m = 0; m < 4; ++m)
                #pragma unroll
                for (int r = 0; r < 4; ++r) acc[m][r] = (f32x4){0.f, 0.f, 0.f, 0.f};
            cb += 1; tap = 0;
        } else {
            tap += 1;
        }

        if (s < 26) {
            __syncthreads();
            *reinterpret_cast<uint4*>(&w_s[wdst0]) = wpre0;
            *reinterpret_cast<uint4*>(&w_s[wdst1]) = wpre1;
            __syncthreads();
        }
    }
}

// ---------------------------------------------------------------------------
// Partial Gram: Ap[pc][h*64+n][m] = sum over this block's 64 pixels of q.k.
// No atomics; softmax reduces the 128 pc partials.
// ---------------------------------------------------------------------------
__launch_bounds__(256)
__global__ void a_mfma_kernel(const unsigned short* __restrict__ qk_buf,
                              float* __restrict__ Ap)
{
    __shared__ __align__(16) unsigned short q_s[64 * 64];   // 8 KB
    __shared__ __align__(16) unsigned short k_s[64 * 64];   // 8 KB
    const int t  = threadIdx.x;
    const int pc = blockIdx.x;   // 0..127
    const int h  = blockIdx.y;   // 0..7
    const int p0 = pc * 64;
    const int lane15 = t & 15, lg = (t >> 4) & 3, wid = t >> 6;
    const int nh = wid >> 1, mh = wid & 1;

    f32x4 acc[2][2];
    #pragma unroll
    for (int a = 0; a < 2; ++a)
        #pragma unroll
        for (int b = 0; b < 2; ++b) acc[a][b] = (f32x4){0.f, 0.f, 0.f, 0.f};

    for (int c = 0; c < 16; ++c) {
        __syncthreads();
        #pragma unroll
        for (int i = 0; i < 4; ++i) {
            const int id = t + i * 256;          // 0..1023
            const int arr = id >> 9, rem = id & 511;
            const int nn = rem >> 3, g = rem & 7;
            const int ch = h * 32 + arr * 16 + c;
            const uint4 v = *reinterpret_cast<const uint4*>(
                &qk_buf[((size_t)nn * 256 + ch) * HW + p0 + g * 8]);
            unsigned short* dstbuf = arr ? k_s : q_s;
            *reinterpret_cast<uint4*>(&dstbuf[nn * 64 + ((g ^ (nn & 7)) << 3)]) = v;
        }
        __syncthreads();
        #pragma unroll
        for (int kk = 0; kk < 2; ++kk) {
            short8 aq[2], bk[2];
            #pragma unroll
            for (int ai = 0; ai < 2; ++ai) {
                const int nl = nh * 32 + ai * 16 + lane15;
                aq[ai] = *reinterpret_cast<const short8*>(
                    &q_s[nl * 64 + (((kk * 4 + lg) ^ (nl & 7)) << 3)]);
            }
            #pragma unroll
            for (int bj = 0; bj < 2; ++bj) {
                const int ml = mh * 32 + bj * 16 + lane15;
                bk[bj] = *reinterpret_cast<const short8*>(
                    &k_s[ml * 64 + (((kk * 4 + lg) ^ (ml & 7)) << 3)]);
            }
            #pragma unroll
            for (int ai = 0; ai < 2; ++ai)
                #pragma unroll
                for (int bj = 0; bj < 2; ++bj)
                    acc[ai][bj] = __builtin_amdgcn_mfma_f32_16x16x32_bf16(
                        aq[ai], bk[bj], acc[ai][bj], 0, 0, 0);
        }
    }
    float* dst = Ap + (size_t)pc * 512 * 64 + (size_t)h * 64 * 64;
    #pragma unroll
    for (int ai = 0; ai < 2; ++ai)
        #pragma unroll
        for (int bj = 0; bj < 2; ++bj)
            #pragma unroll
            for (int reg = 0; reg < 4; ++reg) {
                const int nn = nh * 32 + ai * 16 + lg * 4 + reg;
                const int mm = mh * 32 + bj * 16 + lane15;
                dst[nn * 64 + mm] = acc[ai][bj][reg];
            }
}

// ---------------------------------------------------------------------------
// Reduce the 128 pc partials, softmax over m, emit bf16 softA (m-contiguous).
// ---------------------------------------------------------------------------
__global__ void softmax_kernel(const float* __restrict__ Ap,
                               unsigned short* __restrict__ softAb)
{
    const int row  = blockIdx.x;       // 0..511  (h*64+n)
    const int lane = threadIdx.x;      // 0..63   (m)
    float v = 0.f;
    for (int pc = 0; pc < 128; ++pc)
        v += Ap[((size_t)pc * 512 + row) * 64 + lane];
    const float inv_scale = (float)(1.0 / 362.03867196751236); // 1/sqrt(131072)
    v *= inv_scale;
    float mx = v;
    #pragma unroll
    for (int o = 32; o > 0; o >>= 1) mx = fmaxf(mx, __shfl_xor(mx, o, 64));
    float e = expf(v - mx);
    float s = e;
    #pragma unroll
    for (int o = 32; o > 0; o >>= 1) s += __shfl_xor(s, o, 64);
    softAb[row * 64 + lane] = f2b(e / s);
}

// ---------------------------------------------------------------------------
// sa[n][k][p] = sum_m softA[h][n][m] * v[m][k][p]  via MFMA.
// ---------------------------------------------------------------------------
__launch_bounds__(256, 4)
__global__ void sa_mfma_kernel(const unsigned short* __restrict__ v_buf,
                               const unsigned short* __restrict__ softAb,
                               unsigned short* __restrict__ sa_buf)
{
    __shared__ __align__(16) unsigned short v_s[16384];  // 32 KB
    const int t  = threadIdx.x;
    const int pc = blockIdx.x;   // 0..31
    const int k  = blockIdx.y;   // 0..127
    const int p0 = pc * 256;
    const int h  = k >> 4;

    {
        const int m0 = t >> 5;        // m-octet 0..7
        const int p8 = t & 31;        // pixel-octet 0..31
        unsigned short tmp[8][8];
        #pragma unroll
        for (int i = 0; i < 8; ++i) {
            const uint4 vv = *reinterpret_cast<const uint4*>(
                &v_buf[((size_t)(m0 * 8 + i) * 128 + k) * HW + p0 + p8 * 8]);
            const unsigned short* u = reinterpret_cast<const unsigned short*>(&vv);
            #pragma unroll
            for (int j = 0; j < 8; ++j) tmp[i][j] = u[j];
        }
        #pragma unroll
        for (int j = 0; j < 8; ++j) {
            const int p = p8 * 8 + j;
            short8 pk;
            #pragma unroll
            for (int i = 0; i < 8; ++i) pk[i] = (short)tmp[i][j];
            *reinterpret_cast<short8*>(
                &v_s[m0 * 2048 + ((p ^ (m0 & 7) ^ ((p >> 3) & 7)) << 3)]) = pk;
        }
    }
    __syncthreads();

    const int lane15 = t & 15, lg = (t >> 4) & 3, wid = t >> 6;
    const int wp0 = wid * 64;

    f32x4 acc[4][4];   // [pt][nt]
    #pragma unroll
    for (int a = 0; a < 4; ++a)
        #pragma unroll
        for (int b = 0; b < 4; ++b) acc[a][b] = (f32x4){0.f, 0.f, 0.f, 0.f};

    #pragma unroll
    for (int kc = 0; kc < 2; ++kc) {
        const int g = kc * 4 + lg;
        short8 af[4], bf[4];
        #pragma unroll
        for (int pt = 0; pt < 4; ++pt) {
            const int p = wp0 + pt * 16 + lane15;
            af[pt] = *reinterpret_cast<const short8*>(
                &v_s[g * 2048 + ((p ^ (g & 7) ^ ((p >> 3) & 7)) << 3)]);
        }
        #pragma unroll
        for (int nt = 0; nt < 4; ++nt)
            bf[nt] = *reinterpret_cast<const short8*>(
                &softAb[h * 4096 + (nt * 16 + lane15) * 64 + kc * 32 + lg * 8]);
        #pragma unroll
        for (int pt = 0; pt < 4; ++pt)
            #pragma unroll
            for (int nt = 0; nt < 4; ++nt)
                acc[pt][nt] = __builtin_amdgcn_mfma_f32_16x16x32_bf16(
                    af[pt], bf[nt], acc[pt][nt], 0, 0, 0);
    }

    #pragma unroll
    for (int pt = 0; pt < 4; ++pt)
        #pragma unroll
        for (int nt = 0; nt < 4; ++nt) {
            const int nn = nt * 16 + lane15;
            const int p  = wp0 + pt * 16 + lg * 4;
            uint2 o;
            o.x = (unsigned)f2b(acc[pt][nt][0]) | ((unsigned)f2b(acc[pt][nt][1]) << 16);
            o.y = (unsigned)f2b(acc[pt][nt][2]) | ((unsigned)f2b(acc[pt][nt][3]) << 16);
            *reinterpret_cast<uint2*>(
                &sa_buf[((size_t)nn * 128 + k) * HW + p0 + p]) = o;
        }
}

// ---------------------------------------------------------------------------
// out[n][d][p] = sum_k sa[n][k][p] * Wout[k][d] + bout[d]  via MFMA.
// ---------------------------------------------------------------------------
__launch_bounds__(256, 4)
__global__ void out_mfma_kernel(const unsigned short* __restrict__ sa_buf,
                                const unsigned short* __restrict__ Wt,
                                const float* __restrict__ bout,
                                float* __restrict__ out)
{
    __shared__ __align__(16) unsigned short sa_s[16384];  // 32 KB
    const int t  = threadIdx.x;
    const int pc = blockIdx.x;   // 0..63
    const int n  = blockIdx.y;   // 0..63
    const int p0 = pc * 128;

    {
        const int k0 = t >> 4;        // k-octet 0..15
        const int p8 = t & 15;        // pixel-octet 0..15
        unsigned short tmp[8][8];
        #pragma unroll
        for (int i = 0; i < 8; ++i) {
            const uint4 vv = *reinterpret_cast<const uint4*>(
                &sa_buf[((size_t)n * 128 + k0 * 8 + i) * HW + p0 + p8 * 8]);
            const unsigned short* u = reinterpret_cast<const unsigned short*>(&vv);
            #pragma unroll
            for (int j = 0; j < 8; ++j) tmp[i][j] = u[j];
        }
        #pragma unroll
        for (int j = 0; j < 8; ++j) {
            const int p = p8 * 8 + j;
            short8 pk;
            #pragma unroll
            for (int i = 0; i < 8; ++i) pk[i] = (short)tmp[i][j];
            *reinterpret_cast<short8*>(
                &sa_s[k0 * 1024 + ((p ^ (k0 & 7) ^ ((p >> 3) & 7)) << 3)]) = pk;
        }
    }
    __syncthreads();

    const int lane15 = t & 15, lg = (t >> 4) & 3, wid = t >> 6;
    const int wp0 = wid * 32;

    f32x4 acc[2][4];   // [pt][nt]
    #pragma unroll
    for (int a = 0; a < 2; ++a)
        #pragma unroll
        for (int b = 0; b < 4; ++b) acc[a][b] = (f32x4){0.f, 0.f, 0.f, 0.f};

    #pragma unroll
    for (int kc = 0; kc < 4; ++kc) {
        const int g = kc * 4 + lg;           // 0..15
        short8 af[2], bf[4];
        #pragma unroll
        for (int pt = 0; pt < 2; ++pt) {
            const int p = wp0 + pt * 16 + lane15;
            af[pt] = *reinterpret_cast<const short8*>(
                &sa_s[g * 1024 + ((p ^ (g & 7) ^ ((p >> 3) & 7)) << 3)]);
        }
        #pragma unroll
        for (int nt = 0; nt < 4; ++nt)
            bf[nt] = *reinterpret_cast<const short8*>(
                &Wt[(nt * 16 + lane15) * 128 + kc * 32 + lg * 8]);
        #pragma unroll
        for (int pt = 0; pt < 2; ++pt)
            #pragma unroll
            for (int nt = 0; nt < 4; ++nt)
                acc[pt][nt] = __builtin_amdgcn_mfma_f32_16x16x32_bf16(
                    af[pt], bf[nt], acc[pt][nt], 0, 0, 0);
    }

    #pragma unroll
    for (int pt = 0; pt < 2; ++pt)
        #pragma unroll
        for (int nt = 0; nt < 4; ++nt) {
            const int d = nt * 16 + lane15;
            const int p = wp0 + pt * 16 + lg * 4;
            const float bb = bout[d];
            float4 o;
            o.x = acc[pt][nt][0] + bb; o.y = acc[pt][nt][1] + bb;
            o.z = acc[pt][nt][2] + bb; o.w = acc[pt][nt][3] + bb;
            *reinterpret_cast<float4*>(
                &out[((size_t)n * 64 + d) * HW + p0 + p]) = o;
        }
}

// ---------------------------------------------------------------------------
extern "C" void kernel_launch(void* const* d_in, const int* in_sizes, int n_in,
                              void* d_out, int out_size, void* d_ws, size_t ws_size,
                              hipStream_t stream)
{
    const float* x    = (const float*)d_in[0];
    const float* Wqk  = (const float*)d_in[1];
    const float* bqk  = (const float*)d_in[2];
    const float* Wv   = (const float*)d_in[3];
    const float* bv   = (const float*)d_in[4];
    const float* Wout = (const float*)d_in[5];
    const float* bout = (const float*)d_in[6];
    float* out = (float*)d_out;

    char* ws = (char*)d_ws;
    // ws: qk_buf bf16 [64][256][8192] (268435456, reused as sa_buf)
    //     v_buf bf16 [64][128][8192] (134217728) | (unused 131072)
    //     softAb bf16 (65536) | Wb bf16 (442368) | Wt bf16 (16384)
    unsigned short* qk_buf = (unsigned short*)ws;
    unsigned short* v_buf  = (unsigned short*)(ws + 268435456u);
    unsigned short* softAb = (unsigned short*)(ws + 402784256u);
    unsigned short* Wb     = (unsigned short*)(ws + 402849792u);
    unsigned short* Wt     = (unsigned short*)(ws + 403292160u);
    unsigned short* sa_buf = qk_buf;             // overlays dead q/k after A
    // d_out scratch: xb bf16 [0, 67108864); Ap f32 [67108864, 83886080)
    //   xb dead after conv; Ap dead after softmax; both before out_mfma writes.
    unsigned short* xb = (unsigned short*)d_out;
    float*          Ap = (float*)((char*)d_out + 67108864u);

    cast_w_kernel<<<384, 256, 0, stream>>>(Wqk, Wv, Wout, Wb, Wt);
    cast_x_kernel<<<dim3(32, 64), 256, 0, stream>>>(x, xb);
    conv_mfma_kernel<<<2048, 512, 0, stream>>>(xb, Wb, bqk, bv, qk_buf, v_buf);
    a_mfma_kernel<<<dim3(128, 8), 256, 0, stream>>>(qk_buf, Ap);
    softmax_kernel<<<512, 64, 0, stream>>>(Ap, softAb);
    sa_mfma_kernel<<<dim3(32, 128), 256, 0, stream>>>(v_buf, softAb, sa_buf);
    out_mfma_kernel<<<dim3(64, 64), 256, 0, stream>>>(sa_buf, Wt, bout, out);
}

// Round 12
// 537.845 us; speedup vs baseline: 1.5101x; 1.5101x over previous
//
#include <hip/hip_runtime.h>
#include <hip/hip_bf16.h>
#include <stdint.h>

#define HW 8192
typedef short short8 __attribute__((ext_vector_type(8)));
typedef float f32x4 __attribute__((ext_vector_type(4)));

__device__ __forceinline__ float b2f(unsigned short u) {
    union { unsigned int i; float f; } x; x.i = ((unsigned int)u) << 16; return x.f;
}
__device__ __forceinline__ unsigned short f2b(float f) {
    union { float f; unsigned int i; } x; x.f = f;
    unsigned int lsb = (x.i >> 16) & 1u;
    x.i += 0x7fffu + lsb;
    return (unsigned short)(x.i >> 16);
}

// ---------------------------------------------------------------------------
// Wb[tap][co][ci] bf16, co 0..383 (qk then v).  Also Wt[d][k] = bf16(Wout^T).
// ---------------------------------------------------------------------------
__global__ void cast_w_kernel(const float* __restrict__ Wqk,
                              const float* __restrict__ Wv,
                              const float* __restrict__ Wout,
                              unsigned short* __restrict__ Wb,
                              unsigned short* __restrict__ Wt)
{
    const int co = blockIdx.x;            // 0..383
    const int t  = threadIdx.x;
    const float* src = (co < 256) ? (Wqk + (size_t)co * 576)
                                  : (Wv + (size_t)(co - 256) * 576);
    for (int idx = t; idx < 576; idx += 256) {
        const int ci  = idx / 9;
        const int tap = idx - ci * 9;
        Wb[(size_t)tap * (384 * 64) + co * 64 + ci] = f2b(src[idx]);
    }
    if (co < 64 && t < 128) Wt[co * 128 + t] = f2b(Wout[t * 64 + co]);
}

// ---------------------------------------------------------------------------
// x f32 NCHW -> xb bf16 NHWC ([n][pix][ci]), transposed through LDS.
// ---------------------------------------------------------------------------
__launch_bounds__(256)
__global__ void cast_x_kernel(const float* __restrict__ x,
                              unsigned short* __restrict__ xb)
{
    __shared__ __align__(16) unsigned short xt[256 * 64];   // [p][ci] swizzled
    const int t  = threadIdx.x;
    const int pc = blockIdx.x;   // 0..31
    const int n  = blockIdx.y;
    const size_t p0 = (size_t)pc * 256;

    const int ci0 = (t >> 6) * 16;
    const int pl  = (t & 63) * 4;
    unsigned short tmp[16][4];
    #pragma unroll
    for (int i = 0; i < 16; ++i) {
        const float4 v = *reinterpret_cast<const float4*>(
            x + ((size_t)n * 64 + ci0 + i) * HW + p0 + pl);
        tmp[i][0] = f2b(v.x); tmp[i][1] = f2b(v.y);
        tmp[i][2] = f2b(v.z); tmp[i][3] = f2b(v.w);
    }
    #pragma unroll
    for (int p = 0; p < 4; ++p) {
        const int pp = pl + p;
        #pragma unroll
        for (int half = 0; half < 2; ++half) {
            short8 v;
            #pragma unroll
            for (int j = 0; j < 8; ++j) v[j] = (short)tmp[half * 8 + j][p];
            const int gx = (ci0 >> 3) + half;
            *reinterpret_cast<short8*>(&xt[pp * 64 + ((gx ^ (pp & 7)) << 3)]) = v;
        }
    }
    __syncthreads();
    #pragma unroll
    for (int i = 0; i < 8; ++i) {
        const int id = t + i * 256;
        const int pp = id >> 3, gx = id & 7;
        const uint4 v = *reinterpret_cast<const uint4*>(
            &xt[pp * 64 + ((gx ^ (pp & 7)) << 3)]);
        *reinterpret_cast<uint4*>(
            &xb[((size_t)n * HW + p0 + pp) * 64 + gx * 8]) = v;
    }
}

// ---------------------------------------------------------------------------
// Implicit-GEMM conv (the 280 us / 37% MfmaUtil variant, measured R3/R10).
// Block: 512 thr (8 waves), pixel tile 8x32, co-loop over 3 cb (128 co each).
// x halo (10x34 pos x 64ci) staged once, swizzled.  W single-buffered per tap
// (K=64), reg-prefetched across the barrier.  LDS-transpose epilogue.
// ---------------------------------------------------------------------------
__launch_bounds__(512, 4)
__global__ void conv_mfma_kernel(const unsigned short* __restrict__ xb,
                                 const unsigned short* __restrict__ Wb,
                                 const float* __restrict__ bqk,
                                 const float* __restrict__ bv,
                                 unsigned short* __restrict__ qk_buf,
                                 unsigned short* __restrict__ v_buf)
{
    __shared__ __align__(16) unsigned short x_s[340 * 64];   // 43520 B
    __shared__ __align__(16) unsigned short w_s[128 * 64];   // 16384 B (reused as epilogue buf)
    __shared__ float bias_s[384];

    const int t   = threadIdx.x;
    const int bid = blockIdx.x;
    const int wg  = (bid & 7) * 256 + (bid >> 3);   // XCD swizzle (2048 % 8 == 0)
    const int tile = wg & 31;
    const int n    = wg >> 5;
    const int i0 = (tile >> 2) * 8;
    const int j0 = (tile & 3) * 32;

    if (t < 384) bias_s[t] = (t < 256) ? bqk[t] : bv[t - 256];

    // ---- stage x halo: 340 positions x 8 granules ----
    for (int id = t; id < 340 * 8; id += 512) {
        const int pos = id >> 3, g = id & 7;
        const int r = pos / 34, c = pos - r * 34;
        const int gi = i0 - 1 + r, gj = j0 - 1 + c;
        uint4 v = {0u, 0u, 0u, 0u};
        if ((unsigned)gi < 64u && (unsigned)gj < 128u)
            v = *reinterpret_cast<const uint4*>(
                &xb[((size_t)n * HW + gi * 128 + gj) * 64 + g * 8]);
        *reinterpret_cast<uint4*>(&x_s[pos * 64 + ((g ^ (pos & 7)) << 3)]) = v;
    }

    // ---- W staging roles ----
    const int wco = t >> 3;        // 0..63 (plus +64 for 2nd task)
    const int wgw = t & 7;
    const int wdst0 = wco * 64 + ((wgw ^ (wco & 7)) << 3);
    const int wdst1 = (wco + 64) * 64 + ((wgw ^ ((wco + 64) & 7)) << 3);

    // stage W for step 0 (cb0, tap0)
    *reinterpret_cast<uint4*>(&w_s[wdst0]) =
        *reinterpret_cast<const uint4*>(&Wb[(size_t)wco * 64 + wgw * 8]);
    *reinterpret_cast<uint4*>(&w_s[wdst1]) =
        *reinterpret_cast<const uint4*>(&Wb[(size_t)(wco + 64) * 64 + wgw * 8]);
    __syncthreads();

    // ---- wave decomposition ----
    const int lane15 = t & 15;
    const int lg     = (t >> 4) & 3;
    const int wid    = t >> 6;
    const int wco0   = (wid >> 2) * 64;
    const int pq     = wid & 3;

    f32x4 acc[4][4];
    #pragma unroll
    for (int m = 0; m < 4; ++m)
        #pragma unroll
        for (int r = 0; r < 4; ++r) acc[m][r] = (f32x4){0.f, 0.f, 0.f, 0.f};

    int cb = 0, tap = 0;
    for (int s = 0; s < 27; ++s) {
        // prefetch next step's W
        uint4 wpre0, wpre1;
        if (s < 26) {
            int tap2 = tap + 1, cb2 = cb;
            if (tap2 == 9) { tap2 = 0; cb2 = cb + 1; }
            const unsigned short* wsrc = Wb + ((size_t)tap2 * 384 + cb2 * 128) * 64;
            wpre0 = *reinterpret_cast<const uint4*>(wsrc + wco * 64 + wgw * 8);
            wpre1 = *reinterpret_cast<const uint4*>(wsrc + (wco + 64) * 64 + wgw * 8);
        }
        const int di = (tap * 11) >> 5;      // tap/3
        const int dj = tap - di * 3;

        #pragma unroll
        for (int kc = 0; kc < 2; ++kc) {
            short8 af[4], bf[4];
            #pragma unroll
            for (int m = 0; m < 4; ++m) {
                const int co_l = wco0 + m * 16 + lane15;
                af[m] = *reinterpret_cast<const short8*>(
                    &w_s[co_l * 64 + (((kc * 4 + lg) ^ (co_l & 7)) << 3)]);
            }
            #pragma unroll
            for (int r = 0; r < 4; ++r) {
                const int pos = (pq * 2 + (r >> 1) + di) * 34 + (r & 1) * 16 + lane15 + dj;
                bf[r] = *reinterpret_cast<const short8*>(
                    &x_s[pos * 64 + (((kc * 4 + lg) ^ (pos & 7)) << 3)]);
            }
            #pragma unroll
            for (int m = 0; m < 4; ++m)
                #pragma unroll
                for (int r = 0; r < 4; ++r)
                    acc[m][r] = __builtin_amdgcn_mfma_f32_16x16x32_bf16(
                        af[m], bf[r], acc[m][r], 0, 0, 0);
        }

        if (tap == 8) {
            // ---- epilogue for this cb: transpose through w_s, 64B stores ----
            const bool is_v = (cb == 2);
            #pragma unroll
            for (int p4 = 0; p4 < 4; ++p4) {
                __syncthreads();
                const int hb = p4 >> 1, mp = (p4 & 1) * 2;
                if ((wid >> 2) == hb) {
                    #pragma unroll
                    for (int mi = 0; mi < 2; ++mi) {
                        #pragma unroll
                        for (int r = 0; r < 4; ++r) {
                            const int pix = (pq * 2 + (r >> 1)) * 32 + (r & 1) * 16 + lane15;
                            #pragma unroll
                            for (int reg = 0; reg < 4; ++reg) {
                                const int cw = mi * 16 + lg * 4 + reg;
                                const int co_tile = hb * 64 + mp * 16 + cw;
                                float v;
                                if (p4 == 0)      v = acc[0 + mi][r][reg];
                                else if (p4 == 1) v = acc[2 + mi][r][reg];
                                else if (p4 == 2) v = acc[0 + mi][r][reg];
                                else              v = acc[2 + mi][r][reg];
                                w_s[cw * 256 + pix] = f2b(v + bias_s[cb * 128 + co_tile]);
                            }
                        }
                    }
                }
                __syncthreads();
                #pragma unroll
                for (int i = 0; i < 2; ++i) {
                    const int e = t * 2 + i;
                    const int co_w = e >> 5, ch = e & 31;
                    const int pix0 = ch * 8;
                    const uint4 v = *reinterpret_cast<const uint4*>(&w_s[co_w * 256 + pix0]);
                    const int co_tile = p4 * 32 + co_w;
                    const int row = pix0 >> 5, cc = pix0 & 31;
                    unsigned short* dst = is_v
                        ? (v_buf + ((size_t)n * 128 + co_tile) * HW)
                        : (qk_buf + ((size_t)n * 256 + cb * 128 + co_tile) * HW);
                    *reinterpret_cast<uint4*>(&dst[(i0 + row) * 128 + j0 + cc]) = v;
                }
            }
            #pragma unroll
            for (int m = 0; m < 4; ++m)
                #pragma unroll
                for (int r = 0; r < 4; ++r) acc[m][r] = (f32x4){0.f, 0.f, 0.f, 0.f};
            cb += 1; tap = 0;
        } else {
            tap += 1;
        }

        if (s < 26) {
            __syncthreads();
            *reinterpret_cast<uint4*>(&w_s[wdst0]) = wpre0;
            *reinterpret_cast<uint4*>(&w_s[wdst1]) = wpre1;
            __syncthreads();
        }
    }
}

// ---------------------------------------------------------------------------
// A[h][n][m] = sum_{c,p} q.k via MFMA; split-K over 128 pixel chunks (64 px
// each) for 4 blocks/CU occupancy; atomicAdd.
// ---------------------------------------------------------------------------
__launch_bounds__(256)
__global__ void a_mfma_kernel(const unsigned short* __restrict__ qk_buf,
                              float* __restrict__ A)
{
    __shared__ __align__(16) unsigned short q_s[64 * 64];   // 8 KB
    __shared__ __align__(16) unsigned short k_s[64 * 64];   // 8 KB
    const int t  = threadIdx.x;
    const int pc = blockIdx.x;   // 0..127
    const int h  = blockIdx.y;   // 0..7
    const int p0 = pc * 64;
    const int lane15 = t & 15, lg = (t >> 4) & 3, wid = t >> 6;
    const int nh = wid >> 1, mh = wid & 1;

    f32x4 acc[2][2];
    #pragma unroll
    for (int a = 0; a < 2; ++a)
        #pragma unroll
        for (int b = 0; b < 2; ++b) acc[a][b] = (f32x4){0.f, 0.f, 0.f, 0.f};

    for (int c = 0; c < 16; ++c) {
        __syncthreads();
        #pragma unroll
        for (int i = 0; i < 4; ++i) {
            const int id = t + i * 256;          // 0..1023
            const int arr = id >> 9, rem = id & 511;
            const int nn = rem >> 3, g = rem & 7;
            const int ch = h * 32 + arr * 16 + c;
            const uint4 v = *reinterpret_cast<const uint4*>(
                &qk_buf[((size_t)nn * 256 + ch) * HW + p0 + g * 8]);
            unsigned short* dstbuf = arr ? k_s : q_s;
            *reinterpret_cast<uint4*>(&dstbuf[nn * 64 + ((g ^ (nn & 7)) << 3)]) = v;
        }
        __syncthreads();
        #pragma unroll
        for (int kk = 0; kk < 2; ++kk) {
            short8 aq[2], bk[2];
            #pragma unroll
            for (int ai = 0; ai < 2; ++ai) {
                const int nl = nh * 32 + ai * 16 + lane15;
                aq[ai] = *reinterpret_cast<const short8*>(
                    &q_s[nl * 64 + (((kk * 4 + lg) ^ (nl & 7)) << 3)]);
            }
            #pragma unroll
            for (int bj = 0; bj < 2; ++bj) {
                const int ml = mh * 32 + bj * 16 + lane15;
                bk[bj] = *reinterpret_cast<const short8*>(
                    &k_s[ml * 64 + (((kk * 4 + lg) ^ (ml & 7)) << 3)]);
            }
            #pragma unroll
            for (int ai = 0; ai < 2; ++ai)
                #pragma unroll
                for (int bj = 0; bj < 2; ++bj)
                    acc[ai][bj] = __builtin_amdgcn_mfma_f32_16x16x32_bf16(
                        aq[ai], bk[bj], acc[ai][bj], 0, 0, 0);
        }
    }
    #pragma unroll
    for (int ai = 0; ai < 2; ++ai)
        #pragma unroll
        for (int bj = 0; bj < 2; ++bj)
            #pragma unroll
            for (int reg = 0; reg < 4; ++reg) {
                const int nn = nh * 32 + ai * 16 + lg * 4 + reg;
                const int mm = mh * 32 + bj * 16 + lane15;
                atomicAdd(&A[(h * 64 + nn) * 64 + mm], acc[ai][bj][reg]);
            }
}

// ---------------------------------------------------------------------------
// softmax over m; emits bf16 softA (m-contiguous) for MFMA B-fragments.
// ---------------------------------------------------------------------------
__global__ void softmax_kernel(const float* __restrict__ A,
                               unsigned short* __restrict__ softAb)
{
    const int row  = blockIdx.x;       // 0..511
    const int lane = threadIdx.x;      // 0..63
    const float inv_scale = (float)(1.0 / 362.03867196751236); // 1/sqrt(131072)
    float v = A[row * 64 + lane] * inv_scale;
    float mx = v;
    #pragma unroll
    for (int o = 32; o > 0; o >>= 1) mx = fmaxf(mx, __shfl_xor(mx, o, 64));
    float e = expf(v - mx);
    float s = e;
    #pragma unroll
    for (int o = 32; o > 0; o >>= 1) s += __shfl_xor(s, o, 64);
    softAb[row * 64 + lane] = f2b(e / s);
}

// ---------------------------------------------------------------------------
// sa[n][k][p] = sum_m softA[h][n][m] * v[m][k][p]  via MFMA.
// ---------------------------------------------------------------------------
__launch_bounds__(256, 4)
__global__ void sa_mfma_kernel(const unsigned short* __restrict__ v_buf,
                               const unsigned short* __restrict__ softAb,
                               unsigned short* __restrict__ sa_buf)
{
    __shared__ __align__(16) unsigned short v_s[16384];  // 32 KB
    const int t  = threadIdx.x;
    const int pc = blockIdx.x;   // 0..31
    const int k  = blockIdx.y;   // 0..127
    const int p0 = pc * 256;
    const int h  = k >> 4;

    {
        const int m0 = t >> 5;        // m-octet 0..7
        const int p8 = t & 31;        // pixel-octet 0..31
        unsigned short tmp[8][8];
        #pragma unroll
        for (int i = 0; i < 8; ++i) {
            const uint4 vv = *reinterpret_cast<const uint4*>(
                &v_buf[((size_t)(m0 * 8 + i) * 128 + k) * HW + p0 + p8 * 8]);
            const unsigned short* u = reinterpret_cast<const unsigned short*>(&vv);
            #pragma unroll
            for (int j = 0; j < 8; ++j) tmp[i][j] = u[j];
        }
        #pragma unroll
        for (int j = 0; j < 8; ++j) {
            const int p = p8 * 8 + j;
            short8 pk;
            #pragma unroll
            for (int i = 0; i < 8; ++i) pk[i] = (short)tmp[i][j];
            *reinterpret_cast<short8*>(
                &v_s[m0 * 2048 + ((p ^ (m0 & 7) ^ ((p >> 3) & 7)) << 3)]) = pk;
        }
    }
    __syncthreads();

    const int lane15 = t & 15, lg = (t >> 4) & 3, wid = t >> 6;
    const int wp0 = wid * 64;

    f32x4 acc[4][4];   // [pt][nt]
    #pragma unroll
    for (int a = 0; a < 4; ++a)
        #pragma unroll
        for (int b = 0; b < 4; ++b) acc[a][b] = (f32x4){0.f, 0.f, 0.f, 0.f};

    #pragma unroll
    for (int kc = 0; kc < 2; ++kc) {
        const int g = kc * 4 + lg;
        short8 af[4], bf[4];
        #pragma unroll
        for (int pt = 0; pt < 4; ++pt) {
            const int p = wp0 + pt * 16 + lane15;
            af[pt] = *reinterpret_cast<const short8*>(
                &v_s[g * 2048 + ((p ^ (g & 7) ^ ((p >> 3) & 7)) << 3)]);
        }
        #pragma unroll
        for (int nt = 0; nt < 4; ++nt)
            bf[nt] = *reinterpret_cast<const short8*>(
                &softAb[h * 4096 + (nt * 16 + lane15) * 64 + kc * 32 + lg * 8]);
        #pragma unroll
        for (int pt = 0; pt < 4; ++pt)
            #pragma unroll
            for (int nt = 0; nt < 4; ++nt)
                acc[pt][nt] = __builtin_amdgcn_mfma_f32_16x16x32_bf16(
                    af[pt], bf[nt], acc[pt][nt], 0, 0, 0);
    }

    #pragma unroll
    for (int pt = 0; pt < 4; ++pt)
        #pragma unroll
        for (int nt = 0; nt < 4; ++nt) {
            const int nn = nt * 16 + lane15;
            const int p  = wp0 + pt * 16 + lg * 4;
            uint2 o;
            o.x = (unsigned)f2b(acc[pt][nt][0]) | ((unsigned)f2b(acc[pt][nt][1]) << 16);
            o.y = (unsigned)f2b(acc[pt][nt][2]) | ((unsigned)f2b(acc[pt][nt][3]) << 16);
            *reinterpret_cast<uint2*>(
                &sa_buf[((size_t)nn * 128 + k) * HW + p0 + p]) = o;
        }
}

// ---------------------------------------------------------------------------
// out[n][d][p] = sum_k sa[n][k][p] * Wout[k][d] + bout[d]  via MFMA.
// ---------------------------------------------------------------------------
__launch_bounds__(256, 4)
__global__ void out_mfma_kernel(const unsigned short* __restrict__ sa_buf,
                                const unsigned short* __restrict__ Wt,
                                const float* __restrict__ bout,
                                float* __restrict__ out)
{
    __shared__ __align__(16) unsigned short sa_s[16384];  // 32 KB
    const int t  = threadIdx.x;
    const int pc = blockIdx.x;   // 0..63
    const int n  = blockIdx.y;   // 0..63
    const int p0 = pc * 128;

    {
        const int k0 = t >> 4;        // k-octet 0..15
        const int p8 = t & 15;        // pixel-octet 0..15
        unsigned short tmp[8][8];
        #pragma unroll
        for (int i = 0; i < 8; ++i) {
            const uint4 vv = *reinterpret_cast<const uint4*>(
                &sa_buf[((size_t)n * 128 + k0 * 8 + i) * HW + p0 + p8 * 8]);
            const unsigned short* u = reinterpret_cast<const unsigned short*>(&vv);
            #pragma unroll
            for (int j = 0; j < 8; ++j) tmp[i][j] = u[j];
        }
        #pragma unroll
        for (int j = 0; j < 8; ++j) {
            const int p = p8 * 8 + j;
            short8 pk;
            #pragma unroll
            for (int i = 0; i < 8; ++i) pk[i] = (short)tmp[i][j];
            *reinterpret_cast<short8*>(
                &sa_s[k0 * 1024 + ((p ^ (k0 & 7) ^ ((p >> 3) & 7)) << 3)]) = pk;
        }
    }
    __syncthreads();

    const int lane15 = t & 15, lg = (t >> 4) & 3, wid = t >> 6;
    const int wp0 = wid * 32;

    f32x4 acc[2][4];   // [pt][nt]
    #pragma unroll
    for (int a = 0; a < 2; ++a)
        #pragma unroll
        for (int b = 0; b < 4; ++b) acc[a][b] = (f32x4){0.f, 0.f, 0.f, 0.f};

    #pragma unroll
    for (int kc = 0; kc < 4; ++kc) {
        const int g = kc * 4 + lg;           // 0..15
        short8 af[2], bf[4];
        #pragma unroll
        for (int pt = 0; pt < 2; ++pt) {
            const int p = wp0 + pt * 16 + lane15;
            af[pt] = *reinterpret_cast<const short8*>(
                &sa_s[g * 1024 + ((p ^ (g & 7) ^ ((p >> 3) & 7)) << 3)]);
        }
        #pragma unroll
        for (int nt = 0; nt < 4; ++nt)
            bf[nt] = *reinterpret_cast<const short8*>(
                &Wt[(nt * 16 + lane15) * 128 + kc * 32 + lg * 8]);
        #pragma unroll
        for (int pt = 0; pt < 2; ++pt)
            #pragma unroll
            for (int nt = 0; nt < 4; ++nt)
                acc[pt][nt] = __builtin_amdgcn_mfma_f32_16x16x32_bf16(
                    af[pt], bf[nt], acc[pt][nt], 0, 0, 0);
    }

    #pragma unroll
    for (int pt = 0; pt < 2; ++pt)
        #pragma unroll
        for (int nt = 0; nt < 4; ++nt) {
            const int d = nt * 16 + lane15;
            const int p = wp0 + pt * 16 + lg * 4;
            const float bb = bout[d];
            float4 o;
            o.x = acc[pt][nt][0] + bb; o.y = acc[pt][nt][1] + bb;
            o.z = acc[pt][nt][2] + bb; o.w = acc[pt][nt][3] + bb;
            *reinterpret_cast<float4*>(
                &out[((size_t)n * 64 + d) * HW + p0 + p]) = o;
        }
}

// ---------------------------------------------------------------------------
extern "C" void kernel_launch(void* const* d_in, const int* in_sizes, int n_in,
                              void* d_out, int out_size, void* d_ws, size_t ws_size,
                              hipStream_t stream)
{
    const float* x    = (const float*)d_in[0];
    const float* Wqk  = (const float*)d_in[1];
    const float* bqk  = (const float*)d_in[2];
    const float* Wv   = (const float*)d_in[3];
    const float* bv   = (const float*)d_in[4];
    const float* Wout = (const float*)d_in[5];
    const float* bout = (const float*)d_in[6];
    float* out = (float*)d_out;

    char* ws = (char*)d_ws;
    // ws: qk_buf bf16 [64][256][8192] (268435456, reused as sa_buf)
    //     v_buf bf16 [64][128][8192] (134217728) | A f32 (131072)
    //     softAb bf16 (65536) | Wb bf16 (442368) | Wt bf16 (16384)
    unsigned short* qk_buf = (unsigned short*)ws;
    unsigned short* v_buf  = (unsigned short*)(ws + 268435456u);
    float*          A      = (float*)(ws + 402653184u);
    unsigned short* softAb = (unsigned short*)(ws + 402784256u);
    unsigned short* Wb     = (unsigned short*)(ws + 402849792u);
    unsigned short* Wt     = (unsigned short*)(ws + 403292160u);
    unsigned short* sa_buf = qk_buf;             // overlays dead q/k after A
    unsigned short* xb = (unsigned short*)d_out; // 134 MB scratch, dead until out_mfma

    hipMemsetAsync(A, 0, 131072, stream);
    cast_w_kernel<<<384, 256, 0, stream>>>(Wqk, Wv, Wout, Wb, Wt);
    cast_x_kernel<<<dim3(32, 64), 256, 0, stream>>>(x, xb);
    conv_mfma_kernel<<<2048, 512, 0, stream>>>(xb, Wb, bqk, bv, qk_buf, v_buf);
    a_mfma_kernel<<<dim3(128, 8), 256, 0, stream>>>(qk_buf, A);
    softmax_kernel<<<512, 64, 0, stream>>>(A, softAb);
    sa_mfma_kernel<<<dim3(32, 128), 256, 0, stream>>>(v_buf, softAb, sa_buf);
    out_mfma_kernel<<<dim3(64, 64), 256, 0, stream>>>(sa_buf, Wt, bout, out);
}